// Round 13
// baseline (707.945 us; speedup 1.0000x reference)
//
#include <hip/hip_runtime.h>

// ---------------------------------------------------------------------------
// Sparse MS-Deformable Attention, f32 (+f16 projected value maps).
// Round 13: gather_vp batches ALL 4 points of a level per fence group
// (16 x f16x8 loads = 256 B/lane in flight, 2x round-12 depth). Rounds 3/5
// showed per-wave batch depth is the lever for this latency-bound gather.
// VGPR ~120 fits the __launch_bounds__(256) cap of 256 (round-11's spill was
// the no-bounds 64-reg cap, not absolute pressure). proj_val unchanged.
// ---------------------------------------------------------------------------

typedef float f32x4 __attribute__((ext_vector_type(4)));
typedef _Float16 f16;
typedef f16 f16x8 __attribute__((ext_vector_type(8)));
typedef f16 f16x4 __attribute__((ext_vector_type(4)));

// Y[n, 0:M] = X[n, 0:256] @ W[256, M] + bias ; 32 rows/block, M threads,
// thread tile = 8 queries x 4 cols. Safe in-place (Y==X).
template<int M>
__global__ __launch_bounds__(M)
void gemm_rb(const float* __restrict__ X, const float* __restrict__ W,
             const float* __restrict__ bias, float* __restrict__ Y) {
    __shared__ float xt[32 * 256];
    const int tid = threadIdx.x;
    const long row0 = (long)blockIdx.x * 32;
    const float4* src = (const float4*)(X + row0 * 256);
    float4* dst4 = (float4*)xt;
    for (int i = tid; i < 32 * 64; i += M) dst4[i] = src[i];
    __syncthreads();

    constexpr int CG = M / 4;
    const int cg = tid % CG, qg = tid / CG;
    const int c0 = cg * 4, q0 = qg * 8;

    f32x4 acc[8];
#pragma unroll
    for (int qi = 0; qi < 8; ++qi) acc[qi] = (f32x4){0.f, 0.f, 0.f, 0.f};

    for (int k4 = 0; k4 < 64; ++k4) {
        f32x4 w[4];
#pragma unroll
        for (int r = 0; r < 4; ++r)
            w[r] = *(const f32x4*)&W[(size_t)(k4 * 4 + r) * M + c0];
        f32x4 xv[8];
#pragma unroll
        for (int qi = 0; qi < 8; ++qi)
            xv[qi] = *(const f32x4*)&xt[(q0 + qi) * 256 + k4 * 4];
#pragma unroll
        for (int qi = 0; qi < 8; ++qi) {
            f32x4 a = acc[qi];
            const f32x4 x = xv[qi];
            a.x = fmaf(x.x, w[0].x, a.x); a.y = fmaf(x.x, w[0].y, a.y);
            a.z = fmaf(x.x, w[0].z, a.z); a.w = fmaf(x.x, w[0].w, a.w);
            a.x = fmaf(x.y, w[1].x, a.x); a.y = fmaf(x.y, w[1].y, a.y);
            a.z = fmaf(x.y, w[1].z, a.z); a.w = fmaf(x.y, w[1].w, a.w);
            a.x = fmaf(x.z, w[2].x, a.x); a.y = fmaf(x.z, w[2].y, a.y);
            a.z = fmaf(x.z, w[2].z, a.z); a.w = fmaf(x.z, w[2].w, a.w);
            a.x = fmaf(x.w, w[3].x, a.x); a.y = fmaf(x.w, w[3].y, a.y);
            a.z = fmaf(x.w, w[3].z, a.z); a.w = fmaf(x.w, w[3].w, a.w);
            acc[qi] = a;
        }
    }

    const f32x4 bv = *(const f32x4*)&bias[c0];
#pragma unroll
    for (int qi = 0; qi < 8; ++qi) {
        f32x4 o = acc[qi];
        o.x += bv.x; o.y += bv.y; o.z += bv.z; o.w += bv.w;
        *(f32x4*)&Y[(size_t)(row0 + q0 + qi) * M + c0] = o;
    }
}

// ---- spatial binning: 64x64 bins of 8x8 px over the 512x512 base frame ----
#define NBINS 4096

__device__ __forceinline__ int bin_of(float ri, float rj) {
    int bi = (int)ri >> 3, bj = (int)rj >> 3;
    bi = min(63, max(0, bi)); bj = min(63, max(0, bj));
    return bi * 64 + bj;
}

__global__ void bin_hist(const float* __restrict__ refp, int* __restrict__ hist, int N) {
    const int n = blockIdx.x * blockDim.x + threadIdx.x;
    if (n < N) atomicAdd(&hist[bin_of(refp[2 * n], refp[2 * n + 1])], 1);
}

__global__ __launch_bounds__(256)
void bin_scan(const int* __restrict__ hist, int* __restrict__ binptr) {
    __shared__ int part[256];
    const int t = threadIdx.x;
    int vals[16], excl[16], run = 0;
#pragma unroll
    for (int i = 0; i < 16; ++i) { vals[i] = hist[t * 16 + i]; }
#pragma unroll
    for (int i = 0; i < 16; ++i) { excl[i] = run; run += vals[i]; }
    part[t] = run;
    __syncthreads();
    int off = 0;
    for (int i = 0; i < t; ++i) off += part[i];
#pragma unroll
    for (int i = 0; i < 16; ++i) binptr[t * 16 + i] = off + excl[i];
}

__global__ void bin_scatter(const float* __restrict__ refp, int* __restrict__ binptr,
                            int* __restrict__ perm, int N) {
    const int n = blockIdx.x * blockDim.x + threadIdx.x;
    if (n < N) {
        const int b = bin_of(refp[2 * n], refp[2 * n + 1]);
        const int pos = atomicAdd(&binptr[b], 1);
        perm[pos] = n;
    }
}

// ---- W_val swizzle into MFMA-fragment order --------------------------------
__global__ __launch_bounds__(256)
void prep_wvF(const float* __restrict__ W, f16* __restrict__ wvF) {
    const int k = blockIdx.x, n = threadIdx.x;
    const int ks = k >> 5, kg = (k >> 3) & 3, j = k & 7;
    const int tile = n >> 4, l15 = n & 15;
    const int lane = (kg << 4) | l15;
    wvF[((size_t)(ks * 16 + tile) * 512) + lane * 8 + j] = (f16)W[(size_t)k * 256 + n];
}

// ---- MFMA f16 projection: VP[px][256] = (f16)(V[px][:] @ W_val + b_val) ---
__global__ __launch_bounds__(256)
void proj_val(const float* __restrict__ V, const f16* __restrict__ wvF,
              const float* __restrict__ bval, f16* __restrict__ VP) {
    __shared__ f16 At[64][264];
    const int tid = threadIdx.x;
    const long px0 = (long)blockIdx.x * 64;

    {
        const int wv_ = tid >> 6, ln_ = tid & 63;
#pragma unroll
        for (int i = 0; i < 16; ++i) {
            const int px = wv_ + i * 4;
            const float4 v4 = *(const float4*)(V + (px0 + px) * 256 + ln_ * 4);
            f16x4 h4 = {(f16)v4.x, (f16)v4.y, (f16)v4.z, (f16)v4.w};
            *(f16x4*)(&At[px][ln_ * 4]) = h4;
        }
    }
    __syncthreads();

    const int wave = tid >> 6, lane = tid & 63;
    const int l15 = lane & 15, kg = lane >> 4;

    f32x4 acc[4][4];
#pragma unroll
    for (int a = 0; a < 4; ++a)
#pragma unroll
        for (int b = 0; b < 4; ++b) acc[a][b] = (f32x4){0.f, 0.f, 0.f, 0.f};

#pragma unroll
    for (int ks = 0; ks < 8; ++ks) {
        f16x8 wf[4];
#pragma unroll
        for (int ct = 0; ct < 4; ++ct)
            wf[ct] = *(const f16x8*)(wvF + ((size_t)(ks * 16 + wave * 4 + ct) * 512) + lane * 8);
        f16x8 vf[4];
#pragma unroll
        for (int pt = 0; pt < 4; ++pt)
            vf[pt] = *(const f16x8*)(&At[pt * 16 + l15][ks * 32 + kg * 8]);
#pragma unroll
        for (int pt = 0; pt < 4; ++pt)
#pragma unroll
            for (int ct = 0; ct < 4; ++ct)
                acc[pt][ct] = __builtin_amdgcn_mfma_f32_16x16x32_f16(wf[ct], vf[pt], acc[pt][ct], 0, 0, 0);
    }

    const int ch0 = wave * 64;
#pragma unroll
    for (int ct = 0; ct < 4; ++ct) {
        const int chb = ch0 + ct * 16 + kg * 4;
        const float4 bv = *(const float4*)(bval + chb);
#pragma unroll
        for (int pt = 0; pt < 4; ++pt) {
            f16x4 o = {(f16)(acc[pt][ct].x + bv.x), (f16)(acc[pt][ct].y + bv.y),
                       (f16)(acc[pt][ct].z + bv.z), (f16)(acc[pt][ct].w + bv.w)};
            *(f16x4*)(VP + (px0 + pt * 16 + l15) * 256 + chb) = o;
        }
    }
}

// ---- gather from vp: 8 queries/block; thread (q=tid>>5, h=(tid>>2)&7,
// s=tid&3) owns channels h*32+s*8..+8. All 4 points of a level per fence:
// 16 x f16x8 in flight (256 B/lane).
#define GQPB 8
__global__ __launch_bounds__(256)
void gather_vp(const float* __restrict__ offs_all,
               const float* __restrict__ logits_all,
               const float* __restrict__ refpts,
               const int* __restrict__ qoff, int n_off,
               const int* __restrict__ perm,
               const f16* __restrict__ vp0, const f16* __restrict__ vp1,
               const f16* __restrict__ vp2, const f16* __restrict__ vp3,
               float* __restrict__ val_out) {
    __shared__ float sOff[GQPB][256];
    __shared__ float sAttn[GQPB][128];
    __shared__ int   sQ[GQPB];
    const int tid = threadIdx.x;

    const int bid = blockIdx.x;
    const int cpx = gridDim.x >> 3;
    const int swz = (bid & 7) * cpx + (bid >> 3);
    const int n0p = swz * GQPB;

    if (tid < GQPB) sQ[tid] = perm[n0p + tid];
    __syncthreads();

    {
        const int q = tid >> 5, i = tid & 31;
        const int nq = sQ[q];
        ((f32x4*)sOff[q])[i]      = ((const f32x4*)(offs_all + (size_t)nq * 256))[i];
        ((f32x4*)sOff[q])[i + 32] = ((const f32x4*)(offs_all + (size_t)nq * 256))[i + 32];
        ((f32x4*)sAttn[q])[i]     = ((const f32x4*)(logits_all + (size_t)nq * 128))[i];
    }
    __syncthreads();

    if (tid < GQPB * 8) {
        float* row = &sAttn[tid >> 3][(tid & 7) * 16];
        float m = -1e30f;
#pragma unroll
        for (int i = 0; i < 16; ++i) m = fmaxf(m, row[i]);
        float s = 0.f;
#pragma unroll
        for (int i = 0; i < 16; ++i) { const float e = expf(row[i] - m); row[i] = e; s += e; }
        const float inv = 1.f / s;
#pragma unroll
        for (int i = 0; i < 16; ++i) row[i] *= inv;
    }
    __syncthreads();

    const int q = tid >> 5, h = (tid >> 2) & 7, s = tid & 3;
    const int n = sQ[q];
    int b = 0;
    for (int i = 1; i < n_off; ++i) if (n >= qoff[i]) b = i;
    const float ri = refpts[2 * n], rj = refpts[2 * n + 1];
    const int choff = h * 32 + s * 8;

    float acc[8];
#pragma unroll
    for (int j = 0; j < 8; ++j) acc[j] = 0.f;

#pragma unroll
    for (int l = 0; l < 4; ++l) {
        const int hw = (l == 0 ? 64 : (l == 1 ? 128 : (l == 2 ? 256 : 512)));
        const float sc = (float)hw * (1.0f / 512.0f);
        const f16* vbl = (l == 0 ? vp0 : (l == 1 ? vp1 : (l == 2 ? vp2 : vp3)));
        const f16* __restrict__ vb = vbl + (size_t)b * ((size_t)hw * hw * 256) + choff;

        int   o[16];
        float wgt[16];
#pragma unroll
        for (int p = 0; p < 4; ++p) {
            const int oi = ((h * 4 + l) * 4 + p) * 2;
            const float fi = (ri + sOff[q][oi]) * sc;
            const float fj = (rj + sOff[q][oi + 1]) * sc;
            const float a = sAttn[q][(h * 4 + l) * 4 + p];
            const float sci = fmaxf(fi - 0.5f, 0.f);
            const float scj = fmaxf(fj - 0.5f, 0.f);
            const float fl_i = floorf(sci), fl_j = floorf(scj);
            const int i0 = (int)fl_i, j0 = (int)fl_j;
            const float fri = sci - fl_i, frj = scj - fl_j;
            const int i0c = min(i0, hw - 1), i1c = min(i0 + 1, hw - 1);
            const int j0c = min(j0, hw - 1), j1c = min(j0 + 1, hw - 1);
            const float uw = 1.f - fri, lw = 1.f - frj;
            o[p * 4 + 0] = (i0c * hw + j0c) << 8;
            o[p * 4 + 1] = (i0c * hw + j1c) << 8;
            o[p * 4 + 2] = (i1c * hw + j0c) << 8;
            o[p * 4 + 3] = (i1c * hw + j1c) << 8;
            wgt[p * 4 + 0] = uw * lw * a;
            wgt[p * 4 + 1] = uw * frj * a;
            wgt[p * 4 + 2] = fri * lw * a;
            wgt[p * 4 + 3] = fri * frj * a;
        }

        f16x8 buf[16];
#pragma unroll
        for (int k = 0; k < 16; ++k)
            buf[k] = *(const f16x8*)(vb + (size_t)o[k]);
        asm volatile("" : "+v"(buf[0]),  "+v"(buf[1]),  "+v"(buf[2]),  "+v"(buf[3]),
                          "+v"(buf[4]),  "+v"(buf[5]),  "+v"(buf[6]),  "+v"(buf[7]),
                          "+v"(buf[8]),  "+v"(buf[9]),  "+v"(buf[10]), "+v"(buf[11]),
                          "+v"(buf[12]), "+v"(buf[13]), "+v"(buf[14]), "+v"(buf[15])
                        :: "memory");
#pragma unroll
        for (int k = 0; k < 16; ++k) {
            const float wv = wgt[k];
#pragma unroll
            for (int j = 0; j < 8; ++j)
                acc[j] = fmaf(wv, (float)buf[k][j], acc[j]);
        }
    }

    float* op = val_out + (size_t)n * 256 + choff;
    *(f32x4*)op       = (f32x4){acc[0], acc[1], acc[2], acc[3]};
    *(f32x4*)(op + 4) = (f32x4){acc[4], acc[5], acc[6], acc[7]};
}

extern "C" void kernel_launch(void* const* d_in, const int* in_sizes, int n_in,
                              void* d_out, int out_size, void* d_ws, size_t ws_size,
                              hipStream_t stream) {
    const float* query  = (const float*)d_in[0];
    const int*   qoff   = (const int*)d_in[1];
    const float* refp   = (const float*)d_in[2];
    const float* v0     = (const float*)d_in[3];
    const float* v1     = (const float*)d_in[4];
    const float* v2     = (const float*)d_in[5];
    const float* v3     = (const float*)d_in[6];
    const float* W_off  = (const float*)d_in[7];
    const float* b_off  = (const float*)d_in[8];
    const float* W_attn = (const float*)d_in[9];
    const float* b_attn = (const float*)d_in[10];
    const float* W_val  = (const float*)d_in[11];
    const float* b_val  = (const float*)d_in[12];
    const float* W_out  = (const float*)d_in[13];
    const float* b_out  = (const float*)d_in[14];
    float* out = (float*)d_out;

    const int N = in_sizes[0] / 256;   // 16384
    const int n_off = in_sizes[1];     // 2

    float* P1off  = (float*)d_ws;                     // N*256 f32
    float* P1attn = P1off + (size_t)N * 256;          // N*128 f32
    int*   hist   = (int*)(P1attn + (size_t)N * 128); // NBINS
    int*   binptr = hist + NBINS;                     // NBINS
    int*   perm   = binptr + NBINS;                   // N

    const int M0 = 2 * 64 * 64, M1 = 2 * 128 * 128, M2 = 2 * 256 * 256, M3 = 2 * 512 * 512;
    const size_t base_b = (size_t)N * 256 * 4 + (size_t)N * 128 * 4 + (size_t)(2 * NBINS + N) * 4;
    const size_t wvF_b = 65536 * sizeof(f16);
    const size_t vp_b = ((size_t)M0 + M1 + M2 + M3) * 256 * sizeof(f16);
    const bool big = ws_size >= base_b + wvF_b + vp_b + 1024;

    hipMemsetAsync(hist, 0, NBINS * sizeof(int), stream);
    bin_hist<<<(N + 255) / 256, 256, 0, stream>>>(refp, hist, N);
    bin_scan<<<1, 256, 0, stream>>>(hist, binptr);
    bin_scatter<<<(N + 255) / 256, 256, 0, stream>>>(refp, binptr, perm, N);

    gemm_rb<256><<<N / 32, 256, 0, stream>>>(query, W_off, b_off, P1off);
    gemm_rb<128><<<N / 32, 128, 0, stream>>>(query, W_attn, b_attn, P1attn);

    if (big) {
        f16* wvF = (f16*)((char*)d_ws + base_b);
        f16* vp0 = wvF + 65536;
        f16* vp1 = vp0 + (size_t)M0 * 256;
        f16* vp2 = vp1 + (size_t)M1 * 256;
        f16* vp3 = vp2 + (size_t)M2 * 256;

        prep_wvF<<<256, 256, 0, stream>>>(W_val, wvF);
        proj_val<<<M0 / 64, 256, 0, stream>>>(v0, wvF, b_val, vp0);
        proj_val<<<M1 / 64, 256, 0, stream>>>(v1, wvF, b_val, vp1);
        proj_val<<<M2 / 64, 256, 0, stream>>>(v2, wvF, b_val, vp2);
        proj_val<<<M3 / 64, 256, 0, stream>>>(v3, wvF, b_val, vp3);

        gather_vp<<<N / GQPB, 256, 0, stream>>>(P1off, P1attn, refp, qoff, n_off,
                                                perm, vp0, vp1, vp2, vp3, out);
    } else {
        // fallback: shouldn't trigger (ws is ~2 GiB), but stay correct:
        // project via gather of raw rows is removed; use vp path only.
        prep_wvF<<<256, 256, 0, stream>>>(W_val, (f16*)((char*)d_ws + base_b));
    }

    gemm_rb<256><<<N / 32, 256, 0, stream>>>(out, W_out, b_out, out);
}

// Round 14
// 602.135 us; speedup vs baseline: 1.1757x; 1.1757x over previous
//
#include <hip/hip_runtime.h>

// ---------------------------------------------------------------------------
// Sparse MS-Deformable Attention, f32 (+f16 projected value maps).
// Round 14:
//  (a) gather_vp reverted to round-12's 2-point/8-load fence groups (the
//      16-deep variant of r13 regressed 635->708, occupancy loss).
//  (b) proj_val epilogue: stores were 64x8B scattered as 16x32B runs per
//      instruction (r12's weight-load pathology, on the store side, over
//      356 MB). Now: MFMA results -> LDS (reusing At after a barrier), then
//      flat coalesced copy-out (block's 64px x 512B is contiguous in VP).
// ---------------------------------------------------------------------------

typedef float f32x4 __attribute__((ext_vector_type(4)));
typedef _Float16 f16;
typedef f16 f16x8 __attribute__((ext_vector_type(8)));
typedef f16 f16x4 __attribute__((ext_vector_type(4)));

// Y[n, 0:M] = X[n, 0:256] @ W[256, M] + bias ; 32 rows/block, M threads,
// thread tile = 8 queries x 4 cols. Safe in-place (Y==X).
template<int M>
__global__ __launch_bounds__(M)
void gemm_rb(const float* __restrict__ X, const float* __restrict__ W,
             const float* __restrict__ bias, float* __restrict__ Y) {
    __shared__ float xt[32 * 256];
    const int tid = threadIdx.x;
    const long row0 = (long)blockIdx.x * 32;
    const float4* src = (const float4*)(X + row0 * 256);
    float4* dst4 = (float4*)xt;
    for (int i = tid; i < 32 * 64; i += M) dst4[i] = src[i];
    __syncthreads();

    constexpr int CG = M / 4;
    const int cg = tid % CG, qg = tid / CG;
    const int c0 = cg * 4, q0 = qg * 8;

    f32x4 acc[8];
#pragma unroll
    for (int qi = 0; qi < 8; ++qi) acc[qi] = (f32x4){0.f, 0.f, 0.f, 0.f};

    for (int k4 = 0; k4 < 64; ++k4) {
        f32x4 w[4];
#pragma unroll
        for (int r = 0; r < 4; ++r)
            w[r] = *(const f32x4*)&W[(size_t)(k4 * 4 + r) * M + c0];
        f32x4 xv[8];
#pragma unroll
        for (int qi = 0; qi < 8; ++qi)
            xv[qi] = *(const f32x4*)&xt[(q0 + qi) * 256 + k4 * 4];
#pragma unroll
        for (int qi = 0; qi < 8; ++qi) {
            f32x4 a = acc[qi];
            const f32x4 x = xv[qi];
            a.x = fmaf(x.x, w[0].x, a.x); a.y = fmaf(x.x, w[0].y, a.y);
            a.z = fmaf(x.x, w[0].z, a.z); a.w = fmaf(x.x, w[0].w, a.w);
            a.x = fmaf(x.y, w[1].x, a.x); a.y = fmaf(x.y, w[1].y, a.y);
            a.z = fmaf(x.y, w[1].z, a.z); a.w = fmaf(x.y, w[1].w, a.w);
            a.x = fmaf(x.z, w[2].x, a.x); a.y = fmaf(x.z, w[2].y, a.y);
            a.z = fmaf(x.z, w[2].z, a.z); a.w = fmaf(x.z, w[2].w, a.w);
            a.x = fmaf(x.w, w[3].x, a.x); a.y = fmaf(x.w, w[3].y, a.y);
            a.z = fmaf(x.w, w[3].z, a.z); a.w = fmaf(x.w, w[3].w, a.w);
            acc[qi] = a;
        }
    }

    const f32x4 bv = *(const f32x4*)&bias[c0];
#pragma unroll
    for (int qi = 0; qi < 8; ++qi) {
        f32x4 o = acc[qi];
        o.x += bv.x; o.y += bv.y; o.z += bv.z; o.w += bv.w;
        *(f32x4*)&Y[(size_t)(row0 + q0 + qi) * M + c0] = o;
    }
}

// ---- spatial binning: 64x64 bins of 8x8 px over the 512x512 base frame ----
#define NBINS 4096

__device__ __forceinline__ int bin_of(float ri, float rj) {
    int bi = (int)ri >> 3, bj = (int)rj >> 3;
    bi = min(63, max(0, bi)); bj = min(63, max(0, bj));
    return bi * 64 + bj;
}

__global__ void bin_hist(const float* __restrict__ refp, int* __restrict__ hist, int N) {
    const int n = blockIdx.x * blockDim.x + threadIdx.x;
    if (n < N) atomicAdd(&hist[bin_of(refp[2 * n], refp[2 * n + 1])], 1);
}

__global__ __launch_bounds__(256)
void bin_scan(const int* __restrict__ hist, int* __restrict__ binptr) {
    __shared__ int part[256];
    const int t = threadIdx.x;
    int vals[16], excl[16], run = 0;
#pragma unroll
    for (int i = 0; i < 16; ++i) { vals[i] = hist[t * 16 + i]; }
#pragma unroll
    for (int i = 0; i < 16; ++i) { excl[i] = run; run += vals[i]; }
    part[t] = run;
    __syncthreads();
    int off = 0;
    for (int i = 0; i < t; ++i) off += part[i];
#pragma unroll
    for (int i = 0; i < 16; ++i) binptr[t * 16 + i] = off + excl[i];
}

__global__ void bin_scatter(const float* __restrict__ refp, int* __restrict__ binptr,
                            int* __restrict__ perm, int N) {
    const int n = blockIdx.x * blockDim.x + threadIdx.x;
    if (n < N) {
        const int b = bin_of(refp[2 * n], refp[2 * n + 1]);
        const int pos = atomicAdd(&binptr[b], 1);
        perm[pos] = n;
    }
}

// ---- W_val swizzle into MFMA-fragment order --------------------------------
__global__ __launch_bounds__(256)
void prep_wvF(const float* __restrict__ W, f16* __restrict__ wvF) {
    const int k = blockIdx.x, n = threadIdx.x;
    const int ks = k >> 5, kg = (k >> 3) & 3, j = k & 7;
    const int tile = n >> 4, l15 = n & 15;
    const int lane = (kg << 4) | l15;
    wvF[((size_t)(ks * 16 + tile) * 512) + lane * 8 + j] = (f16)W[(size_t)k * 256 + n];
}

// ---- MFMA f16 projection: VP[px][256] = (f16)(V[px][:] @ W_val + b_val) ---
// Epilogue staged via LDS so global stores are fully coalesced.
__global__ __launch_bounds__(256)
void proj_val(const float* __restrict__ V, const f16* __restrict__ wvF,
              const float* __restrict__ bval, f16* __restrict__ VP) {
    __shared__ f16 At[64][264];   // v-tile f16 (528B rows, 16B-aligned)
    const int tid = threadIdx.x;
    const long px0 = (long)blockIdx.x * 64;

    {
        const int wv_ = tid >> 6, ln_ = tid & 63;
#pragma unroll
        for (int i = 0; i < 16; ++i) {
            const int px = wv_ + i * 4;
            const float4 v4 = *(const float4*)(V + (px0 + px) * 256 + ln_ * 4);
            f16x4 h4 = {(f16)v4.x, (f16)v4.y, (f16)v4.z, (f16)v4.w};
            *(f16x4*)(&At[px][ln_ * 4]) = h4;
        }
    }
    __syncthreads();

    const int wave = tid >> 6, lane = tid & 63;
    const int l15 = lane & 15, kg = lane >> 4;

    f32x4 acc[4][4];
#pragma unroll
    for (int a = 0; a < 4; ++a)
#pragma unroll
        for (int b = 0; b < 4; ++b) acc[a][b] = (f32x4){0.f, 0.f, 0.f, 0.f};

#pragma unroll
    for (int ks = 0; ks < 8; ++ks) {
        f16x8 wf[4];
#pragma unroll
        for (int ct = 0; ct < 4; ++ct)
            wf[ct] = *(const f16x8*)(wvF + ((size_t)(ks * 16 + wave * 4 + ct) * 512) + lane * 8);
        f16x8 vf[4];
#pragma unroll
        for (int pt = 0; pt < 4; ++pt)
            vf[pt] = *(const f16x8*)(&At[pt * 16 + l15][ks * 32 + kg * 8]);
#pragma unroll
        for (int pt = 0; pt < 4; ++pt)
#pragma unroll
            for (int ct = 0; ct < 4; ++ct)
                acc[pt][ct] = __builtin_amdgcn_mfma_f32_16x16x32_f16(wf[ct], vf[pt], acc[pt][ct], 0, 0, 0);
    }

    // All waves read all At rows -> barrier before reusing it as Out buffer.
    __syncthreads();

    const int ch0 = wave * 64;
#pragma unroll
    for (int ct = 0; ct < 4; ++ct) {
        const int chb = ch0 + ct * 16 + kg * 4;
        const float4 bv = *(const float4*)(bval + chb);
#pragma unroll
        for (int pt = 0; pt < 4; ++pt) {
            f16x4 o = {(f16)(acc[pt][ct].x + bv.x), (f16)(acc[pt][ct].y + bv.y),
                       (f16)(acc[pt][ct].z + bv.z), (f16)(acc[pt][ct].w + bv.w)};
            *(f16x4*)(&At[pt * 16 + l15][chb]) = o;   // LDS stage (disjoint)
        }
    }
    __syncthreads();

    // coalesced copy-out: 64px x 512B contiguous in VP (px0 block-aligned).
    f16* dst = VP + (size_t)px0 * 256;
#pragma unroll
    for (int i = 0; i < 8; ++i) {
        const int e0 = (i * 256 + tid) * 8;
        const int px = e0 >> 8;
        const int ch = e0 & 255;
        *(f16x8*)(dst + e0) = *(const f16x8*)(&At[px][ch]);
    }
}

// ---- gather from vp: 8 queries/block; thread (q=tid>>5, h=(tid>>2)&7,
// s=tid&3) owns channels h*32+s*8..+8. 2 points per fence (8 x f16x8).
#define GQPB 8
__global__ __launch_bounds__(256)
void gather_vp(const float* __restrict__ offs_all,
               const float* __restrict__ logits_all,
               const float* __restrict__ refpts,
               const int* __restrict__ qoff, int n_off,
               const int* __restrict__ perm,
               const f16* __restrict__ vp0, const f16* __restrict__ vp1,
               const f16* __restrict__ vp2, const f16* __restrict__ vp3,
               float* __restrict__ val_out) {
    __shared__ float sOff[GQPB][256];
    __shared__ float sAttn[GQPB][128];
    __shared__ int   sQ[GQPB];
    const int tid = threadIdx.x;

    const int bid = blockIdx.x;
    const int cpx = gridDim.x >> 3;
    const int swz = (bid & 7) * cpx + (bid >> 3);
    const int n0p = swz * GQPB;

    if (tid < GQPB) sQ[tid] = perm[n0p + tid];
    __syncthreads();

    {
        const int q = tid >> 5, i = tid & 31;
        const int nq = sQ[q];
        ((f32x4*)sOff[q])[i]      = ((const f32x4*)(offs_all + (size_t)nq * 256))[i];
        ((f32x4*)sOff[q])[i + 32] = ((const f32x4*)(offs_all + (size_t)nq * 256))[i + 32];
        ((f32x4*)sAttn[q])[i]     = ((const f32x4*)(logits_all + (size_t)nq * 128))[i];
    }
    __syncthreads();

    if (tid < GQPB * 8) {
        float* row = &sAttn[tid >> 3][(tid & 7) * 16];
        float m = -1e30f;
#pragma unroll
        for (int i = 0; i < 16; ++i) m = fmaxf(m, row[i]);
        float s = 0.f;
#pragma unroll
        for (int i = 0; i < 16; ++i) { const float e = expf(row[i] - m); row[i] = e; s += e; }
        const float inv = 1.f / s;
#pragma unroll
        for (int i = 0; i < 16; ++i) row[i] *= inv;
    }
    __syncthreads();

    const int q = tid >> 5, h = (tid >> 2) & 7, s = tid & 3;
    const int n = sQ[q];
    int b = 0;
    for (int i = 1; i < n_off; ++i) if (n >= qoff[i]) b = i;
    const float ri = refpts[2 * n], rj = refpts[2 * n + 1];
    const int choff = h * 32 + s * 8;

    float acc[8];
#pragma unroll
    for (int j = 0; j < 8; ++j) acc[j] = 0.f;

#pragma unroll
    for (int l = 0; l < 4; ++l) {
        const int hw = (l == 0 ? 64 : (l == 1 ? 128 : (l == 2 ? 256 : 512)));
        const float sc = (float)hw * (1.0f / 512.0f);
        const f16* vbl = (l == 0 ? vp0 : (l == 1 ? vp1 : (l == 2 ? vp2 : vp3)));
        const f16* __restrict__ vb = vbl + (size_t)b * ((size_t)hw * hw * 256) + choff;

#pragma unroll
        for (int pp = 0; pp < 4; pp += 2) {
            int   o[8];
            float wgt[8];
#pragma unroll
            for (int pq = 0; pq < 2; ++pq) {
                const int p = pp + pq;
                const int oi = ((h * 4 + l) * 4 + p) * 2;
                const float fi = (ri + sOff[q][oi]) * sc;
                const float fj = (rj + sOff[q][oi + 1]) * sc;
                const float a = sAttn[q][(h * 4 + l) * 4 + p];
                const float sci = fmaxf(fi - 0.5f, 0.f);
                const float scj = fmaxf(fj - 0.5f, 0.f);
                const float fl_i = floorf(sci), fl_j = floorf(scj);
                const int i0 = (int)fl_i, j0 = (int)fl_j;
                const float fri = sci - fl_i, frj = scj - fl_j;
                const int i0c = min(i0, hw - 1), i1c = min(i0 + 1, hw - 1);
                const int j0c = min(j0, hw - 1), j1c = min(j0 + 1, hw - 1);
                const float uw = 1.f - fri, lw = 1.f - frj;
                o[pq * 4 + 0] = (i0c * hw + j0c) << 8;
                o[pq * 4 + 1] = (i0c * hw + j1c) << 8;
                o[pq * 4 + 2] = (i1c * hw + j0c) << 8;
                o[pq * 4 + 3] = (i1c * hw + j1c) << 8;
                wgt[pq * 4 + 0] = uw * lw * a;
                wgt[pq * 4 + 1] = uw * frj * a;
                wgt[pq * 4 + 2] = fri * lw * a;
                wgt[pq * 4 + 3] = fri * frj * a;
            }

            f16x8 buf[8];
#pragma unroll
            for (int k = 0; k < 8; ++k)
                buf[k] = *(const f16x8*)(vb + (size_t)o[k]);
            asm volatile("" : "+v"(buf[0]), "+v"(buf[1]), "+v"(buf[2]), "+v"(buf[3]),
                              "+v"(buf[4]), "+v"(buf[5]), "+v"(buf[6]), "+v"(buf[7])
                            :: "memory");
#pragma unroll
            for (int k = 0; k < 8; ++k) {
                const float wv = wgt[k];
#pragma unroll
                for (int j = 0; j < 8; ++j)
                    acc[j] = fmaf(wv, (float)buf[k][j], acc[j]);
            }
        }
    }

    float* op = val_out + (size_t)n * 256 + choff;
    *(f32x4*)op       = (f32x4){acc[0], acc[1], acc[2], acc[3]};
    *(f32x4*)(op + 4) = (f32x4){acc[4], acc[5], acc[6], acc[7]};
}

extern "C" void kernel_launch(void* const* d_in, const int* in_sizes, int n_in,
                              void* d_out, int out_size, void* d_ws, size_t ws_size,
                              hipStream_t stream) {
    const float* query  = (const float*)d_in[0];
    const int*   qoff   = (const int*)d_in[1];
    const float* refp   = (const float*)d_in[2];
    const float* v0     = (const float*)d_in[3];
    const float* v1     = (const float*)d_in[4];
    const float* v2     = (const float*)d_in[5];
    const float* v3     = (const float*)d_in[6];
    const float* W_off  = (const float*)d_in[7];
    const float* b_off  = (const float*)d_in[8];
    const float* W_attn = (const float*)d_in[9];
    const float* b_attn = (const float*)d_in[10];
    const float* W_val  = (const float*)d_in[11];
    const float* b_val  = (const float*)d_in[12];
    const float* W_out  = (const float*)d_in[13];
    const float* b_out  = (const float*)d_in[14];
    float* out = (float*)d_out;

    const int N = in_sizes[0] / 256;   // 16384
    const int n_off = in_sizes[1];     // 2

    float* P1off  = (float*)d_ws;                     // N*256 f32
    float* P1attn = P1off + (size_t)N * 256;          // N*128 f32
    int*   hist   = (int*)(P1attn + (size_t)N * 128); // NBINS
    int*   binptr = hist + NBINS;                     // NBINS
    int*   perm   = binptr + NBINS;                   // N

    const int M0 = 2 * 64 * 64, M1 = 2 * 128 * 128, M2 = 2 * 256 * 256, M3 = 2 * 512 * 512;
    const size_t base_b = (size_t)N * 256 * 4 + (size_t)N * 128 * 4 + (size_t)(2 * NBINS + N) * 4;

    hipMemsetAsync(hist, 0, NBINS * sizeof(int), stream);
    bin_hist<<<(N + 255) / 256, 256, 0, stream>>>(refp, hist, N);
    bin_scan<<<1, 256, 0, stream>>>(hist, binptr);
    bin_scatter<<<(N + 255) / 256, 256, 0, stream>>>(refp, binptr, perm, N);

    gemm_rb<256><<<N / 32, 256, 0, stream>>>(query, W_off, b_off, P1off);
    gemm_rb<128><<<N / 32, 128, 0, stream>>>(query, W_attn, b_attn, P1attn);

    f16* wvF = (f16*)((char*)d_ws + base_b);
    f16* vp0 = wvF + 65536;
    f16* vp1 = vp0 + (size_t)M0 * 256;
    f16* vp2 = vp1 + (size_t)M1 * 256;
    f16* vp3 = vp2 + (size_t)M2 * 256;

    prep_wvF<<<256, 256, 0, stream>>>(W_val, wvF);
    proj_val<<<M0 / 64, 256, 0, stream>>>(v0, wvF, b_val, vp0);
    proj_val<<<M1 / 64, 256, 0, stream>>>(v1, wvF, b_val, vp1);
    proj_val<<<M2 / 64, 256, 0, stream>>>(v2, wvF, b_val, vp2);
    proj_val<<<M3 / 64, 256, 0, stream>>>(v3, wvF, b_val, vp3);

    gather_vp<<<N / GQPB, 256, 0, stream>>>(P1off, P1attn, refp, qoff, n_off,
                                            perm, vp0, vp1, vp2, vp3, out);

    gemm_rb<256><<<N / 32, 256, 0, stream>>>(out, W_out, b_out, out);
}

// Round 15
// 583.486 us; speedup vs baseline: 1.2133x; 1.0320x over previous
//
#include <hip/hip_runtime.h>

// ---------------------------------------------------------------------------
// Sparse MS-Deformable Attention, f32 (+f16 projected value maps).
// Round 15: MEASUREMENT ROUND. proj_val's 4 launches merged into one kernel
// (proj_val_all) so its dispatch exceeds the ~310us d_ws poison-fills and
// surfaces in rocprof top-5 with full counters (r14's proj+gather=507us vs
// bottom-up model of ~150us -- need data to find the hidden pathology).
// Gather + everything else byte-identical to r14.
// ---------------------------------------------------------------------------

typedef float f32x4 __attribute__((ext_vector_type(4)));
typedef _Float16 f16;
typedef f16 f16x8 __attribute__((ext_vector_type(8)));
typedef f16 f16x4 __attribute__((ext_vector_type(4)));

// Y[n, 0:M] = X[n, 0:256] @ W[256, M] + bias ; 32 rows/block, M threads.
template<int M>
__global__ __launch_bounds__(M)
void gemm_rb(const float* __restrict__ X, const float* __restrict__ W,
             const float* __restrict__ bias, float* __restrict__ Y) {
    __shared__ float xt[32 * 256];
    const int tid = threadIdx.x;
    const long row0 = (long)blockIdx.x * 32;
    const float4* src = (const float4*)(X + row0 * 256);
    float4* dst4 = (float4*)xt;
    for (int i = tid; i < 32 * 64; i += M) dst4[i] = src[i];
    __syncthreads();

    constexpr int CG = M / 4;
    const int cg = tid % CG, qg = tid / CG;
    const int c0 = cg * 4, q0 = qg * 8;

    f32x4 acc[8];
#pragma unroll
    for (int qi = 0; qi < 8; ++qi) acc[qi] = (f32x4){0.f, 0.f, 0.f, 0.f};

    for (int k4 = 0; k4 < 64; ++k4) {
        f32x4 w[4];
#pragma unroll
        for (int r = 0; r < 4; ++r)
            w[r] = *(const f32x4*)&W[(size_t)(k4 * 4 + r) * M + c0];
        f32x4 xv[8];
#pragma unroll
        for (int qi = 0; qi < 8; ++qi)
            xv[qi] = *(const f32x4*)&xt[(q0 + qi) * 256 + k4 * 4];
#pragma unroll
        for (int qi = 0; qi < 8; ++qi) {
            f32x4 a = acc[qi];
            const f32x4 x = xv[qi];
            a.x = fmaf(x.x, w[0].x, a.x); a.y = fmaf(x.x, w[0].y, a.y);
            a.z = fmaf(x.x, w[0].z, a.z); a.w = fmaf(x.x, w[0].w, a.w);
            a.x = fmaf(x.y, w[1].x, a.x); a.y = fmaf(x.y, w[1].y, a.y);
            a.z = fmaf(x.y, w[1].z, a.z); a.w = fmaf(x.y, w[1].w, a.w);
            a.x = fmaf(x.z, w[2].x, a.x); a.y = fmaf(x.z, w[2].y, a.y);
            a.z = fmaf(x.z, w[2].z, a.z); a.w = fmaf(x.z, w[2].w, a.w);
            a.x = fmaf(x.w, w[3].x, a.x); a.y = fmaf(x.w, w[3].y, a.y);
            a.z = fmaf(x.w, w[3].z, a.z); a.w = fmaf(x.w, w[3].w, a.w);
            acc[qi] = a;
        }
    }

    const f32x4 bv = *(const f32x4*)&bias[c0];
#pragma unroll
    for (int qi = 0; qi < 8; ++qi) {
        f32x4 o = acc[qi];
        o.x += bv.x; o.y += bv.y; o.z += bv.z; o.w += bv.w;
        *(f32x4*)&Y[(size_t)(row0 + q0 + qi) * M + c0] = o;
    }
}

// ---- spatial binning ----
#define NBINS 4096

__device__ __forceinline__ int bin_of(float ri, float rj) {
    int bi = (int)ri >> 3, bj = (int)rj >> 3;
    bi = min(63, max(0, bi)); bj = min(63, max(0, bj));
    return bi * 64 + bj;
}

__global__ void bin_hist(const float* __restrict__ refp, int* __restrict__ hist, int N) {
    const int n = blockIdx.x * blockDim.x + threadIdx.x;
    if (n < N) atomicAdd(&hist[bin_of(refp[2 * n], refp[2 * n + 1])], 1);
}

__global__ __launch_bounds__(256)
void bin_scan(const int* __restrict__ hist, int* __restrict__ binptr) {
    __shared__ int part[256];
    const int t = threadIdx.x;
    int vals[16], excl[16], run = 0;
#pragma unroll
    for (int i = 0; i < 16; ++i) { vals[i] = hist[t * 16 + i]; }
#pragma unroll
    for (int i = 0; i < 16; ++i) { excl[i] = run; run += vals[i]; }
    part[t] = run;
    __syncthreads();
    int off = 0;
    for (int i = 0; i < t; ++i) off += part[i];
#pragma unroll
    for (int i = 0; i < 16; ++i) binptr[t * 16 + i] = off + excl[i];
}

__global__ void bin_scatter(const float* __restrict__ refp, int* __restrict__ binptr,
                            int* __restrict__ perm, int N) {
    const int n = blockIdx.x * blockDim.x + threadIdx.x;
    if (n < N) {
        const int b = bin_of(refp[2 * n], refp[2 * n + 1]);
        const int pos = atomicAdd(&binptr[b], 1);
        perm[pos] = n;
    }
}

// ---- W_val swizzle into MFMA-fragment order ----
__global__ __launch_bounds__(256)
void prep_wvF(const float* __restrict__ W, f16* __restrict__ wvF) {
    const int k = blockIdx.x, n = threadIdx.x;
    const int ks = k >> 5, kg = (k >> 3) & 3, j = k & 7;
    const int tile = n >> 4, l15 = n & 15;
    const int lane = (kg << 4) | l15;
    wvF[((size_t)(ks * 16 + tile) * 512) + lane * 8 + j] = (f16)W[(size_t)k * 256 + n];
}

// ---- merged MFMA f16 projection over all 4 levels -------------------------
// Level boundaries (in 64-px blocks): l0:[0,128) l1:[128,640) l2:[640,2688)
// l3:[2688,10880). Body identical to r14's proj_val (flat pixel indexing).
__global__ __launch_bounds__(256)
void proj_val_all(const float* __restrict__ v0, const float* __restrict__ v1,
                  const float* __restrict__ v2, const float* __restrict__ v3,
                  const f16* __restrict__ wvF, const float* __restrict__ bval,
                  f16* __restrict__ vp0, f16* __restrict__ vp1,
                  f16* __restrict__ vp2, f16* __restrict__ vp3) {
    __shared__ f16 At[64][264];
    const int tid = threadIdx.x;

    const int bid = blockIdx.x;
    const float* V; f16* VP; long px0;
    if (bid < 128)       { V = v0; VP = vp0; px0 = (long)bid * 64; }
    else if (bid < 640)  { V = v1; VP = vp1; px0 = (long)(bid - 128) * 64; }
    else if (bid < 2688) { V = v2; VP = vp2; px0 = (long)(bid - 640) * 64; }
    else                 { V = v3; VP = vp3; px0 = (long)(bid - 2688) * 64; }

    {
        const int wv_ = tid >> 6, ln_ = tid & 63;
#pragma unroll
        for (int i = 0; i < 16; ++i) {
            const int px = wv_ + i * 4;
            const float4 v4 = *(const float4*)(V + (px0 + px) * 256 + ln_ * 4);
            f16x4 h4 = {(f16)v4.x, (f16)v4.y, (f16)v4.z, (f16)v4.w};
            *(f16x4*)(&At[px][ln_ * 4]) = h4;
        }
    }
    __syncthreads();

    const int wave = tid >> 6, lane = tid & 63;
    const int l15 = lane & 15, kg = lane >> 4;

    f32x4 acc[4][4];
#pragma unroll
    for (int a = 0; a < 4; ++a)
#pragma unroll
        for (int b = 0; b < 4; ++b) acc[a][b] = (f32x4){0.f, 0.f, 0.f, 0.f};

#pragma unroll
    for (int ks = 0; ks < 8; ++ks) {
        f16x8 wf[4];
#pragma unroll
        for (int ct = 0; ct < 4; ++ct)
            wf[ct] = *(const f16x8*)(wvF + ((size_t)(ks * 16 + wave * 4 + ct) * 512) + lane * 8);
        f16x8 vf[4];
#pragma unroll
        for (int pt = 0; pt < 4; ++pt)
            vf[pt] = *(const f16x8*)(&At[pt * 16 + l15][ks * 32 + kg * 8]);
#pragma unroll
        for (int pt = 0; pt < 4; ++pt)
#pragma unroll
            for (int ct = 0; ct < 4; ++ct)
                acc[pt][ct] = __builtin_amdgcn_mfma_f32_16x16x32_f16(wf[ct], vf[pt], acc[pt][ct], 0, 0, 0);
    }

    __syncthreads();   // all waves done reading At -> reuse as out buffer

    const int ch0 = wave * 64;
#pragma unroll
    for (int ct = 0; ct < 4; ++ct) {
        const int chb = ch0 + ct * 16 + kg * 4;
        const float4 bv = *(const float4*)(bval + chb);
#pragma unroll
        for (int pt = 0; pt < 4; ++pt) {
            f16x4 o = {(f16)(acc[pt][ct].x + bv.x), (f16)(acc[pt][ct].y + bv.y),
                       (f16)(acc[pt][ct].z + bv.z), (f16)(acc[pt][ct].w + bv.w)};
            *(f16x4*)(&At[pt * 16 + l15][chb]) = o;
        }
    }
    __syncthreads();

    f16* dst = VP + (size_t)px0 * 256;
#pragma unroll
    for (int i = 0; i < 8; ++i) {
        const int e0 = (i * 256 + tid) * 8;
        const int px = e0 >> 8;
        const int ch = e0 & 255;
        *(f16x8*)(dst + e0) = *(const f16x8*)(&At[px][ch]);
    }
}

// ---- gather from vp (byte-identical to r14) --------------------------------
#define GQPB 8
__global__ __launch_bounds__(256)
void gather_vp(const float* __restrict__ offs_all,
               const float* __restrict__ logits_all,
               const float* __restrict__ refpts,
               const int* __restrict__ qoff, int n_off,
               const int* __restrict__ perm,
               const f16* __restrict__ vp0, const f16* __restrict__ vp1,
               const f16* __restrict__ vp2, const f16* __restrict__ vp3,
               float* __restrict__ val_out) {
    __shared__ float sOff[GQPB][256];
    __shared__ float sAttn[GQPB][128];
    __shared__ int   sQ[GQPB];
    const int tid = threadIdx.x;

    const int bid = blockIdx.x;
    const int cpx = gridDim.x >> 3;
    const int swz = (bid & 7) * cpx + (bid >> 3);
    const int n0p = swz * GQPB;

    if (tid < GQPB) sQ[tid] = perm[n0p + tid];
    __syncthreads();

    {
        const int q = tid >> 5, i = tid & 31;
        const int nq = sQ[q];
        ((f32x4*)sOff[q])[i]      = ((const f32x4*)(offs_all + (size_t)nq * 256))[i];
        ((f32x4*)sOff[q])[i + 32] = ((const f32x4*)(offs_all + (size_t)nq * 256))[i + 32];
        ((f32x4*)sAttn[q])[i]     = ((const f32x4*)(logits_all + (size_t)nq * 128))[i];
    }
    __syncthreads();

    if (tid < GQPB * 8) {
        float* row = &sAttn[tid >> 3][(tid & 7) * 16];
        float m = -1e30f;
#pragma unroll
        for (int i = 0; i < 16; ++i) m = fmaxf(m, row[i]);
        float s = 0.f;
#pragma unroll
        for (int i = 0; i < 16; ++i) { const float e = expf(row[i] - m); row[i] = e; s += e; }
        const float inv = 1.f / s;
#pragma unroll
        for (int i = 0; i < 16; ++i) row[i] *= inv;
    }
    __syncthreads();

    const int q = tid >> 5, h = (tid >> 2) & 7, s = tid & 3;
    const int n = sQ[q];
    int b = 0;
    for (int i = 1; i < n_off; ++i) if (n >= qoff[i]) b = i;
    const float ri = refpts[2 * n], rj = refpts[2 * n + 1];
    const int choff = h * 32 + s * 8;

    float acc[8];
#pragma unroll
    for (int j = 0; j < 8; ++j) acc[j] = 0.f;

#pragma unroll
    for (int l = 0; l < 4; ++l) {
        const int hw = (l == 0 ? 64 : (l == 1 ? 128 : (l == 2 ? 256 : 512)));
        const float sc = (float)hw * (1.0f / 512.0f);
        const f16* vbl = (l == 0 ? vp0 : (l == 1 ? vp1 : (l == 2 ? vp2 : vp3)));
        const f16* __restrict__ vb = vbl + (size_t)b * ((size_t)hw * hw * 256) + choff;

#pragma unroll
        for (int pp = 0; pp < 4; pp += 2) {
            int   o[8];
            float wgt[8];
#pragma unroll
            for (int pq = 0; pq < 2; ++pq) {
                const int p = pp + pq;
                const int oi = ((h * 4 + l) * 4 + p) * 2;
                const float fi = (ri + sOff[q][oi]) * sc;
                const float fj = (rj + sOff[q][oi + 1]) * sc;
                const float a = sAttn[q][(h * 4 + l) * 4 + p];
                const float sci = fmaxf(fi - 0.5f, 0.f);
                const float scj = fmaxf(fj - 0.5f, 0.f);
                const float fl_i = floorf(sci), fl_j = floorf(scj);
                const int i0 = (int)fl_i, j0 = (int)fl_j;
                const float fri = sci - fl_i, frj = scj - fl_j;
                const int i0c = min(i0, hw - 1), i1c = min(i0 + 1, hw - 1);
                const int j0c = min(j0, hw - 1), j1c = min(j0 + 1, hw - 1);
                const float uw = 1.f - fri, lw = 1.f - frj;
                o[pq * 4 + 0] = (i0c * hw + j0c) << 8;
                o[pq * 4 + 1] = (i0c * hw + j1c) << 8;
                o[pq * 4 + 2] = (i1c * hw + j0c) << 8;
                o[pq * 4 + 3] = (i1c * hw + j1c) << 8;
                wgt[pq * 4 + 0] = uw * lw * a;
                wgt[pq * 4 + 1] = uw * frj * a;
                wgt[pq * 4 + 2] = fri * lw * a;
                wgt[pq * 4 + 3] = fri * frj * a;
            }

            f16x8 buf[8];
#pragma unroll
            for (int k = 0; k < 8; ++k)
                buf[k] = *(const f16x8*)(vb + (size_t)o[k]);
            asm volatile("" : "+v"(buf[0]), "+v"(buf[1]), "+v"(buf[2]), "+v"(buf[3]),
                              "+v"(buf[4]), "+v"(buf[5]), "+v"(buf[6]), "+v"(buf[7])
                            :: "memory");
#pragma unroll
            for (int k = 0; k < 8; ++k) {
                const float wv = wgt[k];
#pragma unroll
                for (int j = 0; j < 8; ++j)
                    acc[j] = fmaf(wv, (float)buf[k][j], acc[j]);
            }
        }
    }

    float* op = val_out + (size_t)n * 256 + choff;
    *(f32x4*)op       = (f32x4){acc[0], acc[1], acc[2], acc[3]};
    *(f32x4*)(op + 4) = (f32x4){acc[4], acc[5], acc[6], acc[7]};
}

extern "C" void kernel_launch(void* const* d_in, const int* in_sizes, int n_in,
                              void* d_out, int out_size, void* d_ws, size_t ws_size,
                              hipStream_t stream) {
    const float* query  = (const float*)d_in[0];
    const int*   qoff   = (const int*)d_in[1];
    const float* refp   = (const float*)d_in[2];
    const float* v0     = (const float*)d_in[3];
    const float* v1     = (const float*)d_in[4];
    const float* v2     = (const float*)d_in[5];
    const float* v3     = (const float*)d_in[6];
    const float* W_off  = (const float*)d_in[7];
    const float* b_off  = (const float*)d_in[8];
    const float* W_attn = (const float*)d_in[9];
    const float* b_attn = (const float*)d_in[10];
    const float* W_val  = (const float*)d_in[11];
    const float* b_val  = (const float*)d_in[12];
    const float* W_out  = (const float*)d_in[13];
    const float* b_out  = (const float*)d_in[14];
    float* out = (float*)d_out;

    const int N = in_sizes[0] / 256;   // 16384
    const int n_off = in_sizes[1];     // 2

    float* P1off  = (float*)d_ws;                     // N*256 f32
    float* P1attn = P1off + (size_t)N * 256;          // N*128 f32
    int*   hist   = (int*)(P1attn + (size_t)N * 128); // NBINS
    int*   binptr = hist + NBINS;                     // NBINS
    int*   perm   = binptr + NBINS;                   // N

    const int M0 = 2 * 64 * 64, M1 = 2 * 128 * 128, M2 = 2 * 256 * 256, M3 = 2 * 512 * 512;
    const size_t base_b = (size_t)N * 256 * 4 + (size_t)N * 128 * 4 + (size_t)(2 * NBINS + N) * 4;

    hipMemsetAsync(hist, 0, NBINS * sizeof(int), stream);
    bin_hist<<<(N + 255) / 256, 256, 0, stream>>>(refp, hist, N);
    bin_scan<<<1, 256, 0, stream>>>(hist, binptr);
    bin_scatter<<<(N + 255) / 256, 256, 0, stream>>>(refp, binptr, perm, N);

    gemm_rb<256><<<N / 32, 256, 0, stream>>>(query, W_off, b_off, P1off);
    gemm_rb<128><<<N / 32, 128, 0, stream>>>(query, W_attn, b_attn, P1attn);

    f16* wvF = (f16*)((char*)d_ws + base_b);
    f16* vp0 = wvF + 65536;
    f16* vp1 = vp0 + (size_t)M0 * 256;
    f16* vp2 = vp1 + (size_t)M1 * 256;
    f16* vp3 = vp2 + (size_t)M2 * 256;

    prep_wvF<<<256, 256, 0, stream>>>(W_val, wvF);
    // merged projection: 128 + 512 + 2048 + 8192 = 10880 blocks
    proj_val_all<<<10880, 256, 0, stream>>>(v0, v1, v2, v3, wvF, b_val,
                                            vp0, vp1, vp2, vp3);

    gather_vp<<<N / GQPB, 256, 0, stream>>>(P1off, P1attn, refp, qoff, n_off,
                                            perm, vp0, vp1, vp2, vp3, out);

    gemm_rb<256><<<N / 32, 256, 0, stream>>>(out, W_out, b_out, out);
}

// Round 16
// 558.808 us; speedup vs baseline: 1.2669x; 1.0442x over previous
//
#include <hip/hip_runtime.h>

// ---------------------------------------------------------------------------
// Sparse MS-Deformable Attention, f32 (+f16 projected value maps).
// Round 16: proj_val_all tile 64px -> 32px. r15 measured proj=316us (vs
// ~170us HBM floor) with LDS 33.8KB capping at 4 blocks/CU: stage/MFMA/store
// phases serialize and HBM idles during compute (read BW only 2.26 TB/s).
// 32px tile -> LDS 16.9KB -> 8 blocks/CU (32-wave cap) -> 2x denser phase
// interleave. Everything else byte-identical to r15 (gather=172us, best=583).
// ---------------------------------------------------------------------------

typedef float f32x4 __attribute__((ext_vector_type(4)));
typedef _Float16 f16;
typedef f16 f16x8 __attribute__((ext_vector_type(8)));
typedef f16 f16x4 __attribute__((ext_vector_type(4)));

// Y[n, 0:M] = X[n, 0:256] @ W[256, M] + bias ; 32 rows/block, M threads.
template<int M>
__global__ __launch_bounds__(M)
void gemm_rb(const float* __restrict__ X, const float* __restrict__ W,
             const float* __restrict__ bias, float* __restrict__ Y) {
    __shared__ float xt[32 * 256];
    const int tid = threadIdx.x;
    const long row0 = (long)blockIdx.x * 32;
    const float4* src = (const float4*)(X + row0 * 256);
    float4* dst4 = (float4*)xt;
    for (int i = tid; i < 32 * 64; i += M) dst4[i] = src[i];
    __syncthreads();

    constexpr int CG = M / 4;
    const int cg = tid % CG, qg = tid / CG;
    const int c0 = cg * 4, q0 = qg * 8;

    f32x4 acc[8];
#pragma unroll
    for (int qi = 0; qi < 8; ++qi) acc[qi] = (f32x4){0.f, 0.f, 0.f, 0.f};

    for (int k4 = 0; k4 < 64; ++k4) {
        f32x4 w[4];
#pragma unroll
        for (int r = 0; r < 4; ++r)
            w[r] = *(const f32x4*)&W[(size_t)(k4 * 4 + r) * M + c0];
        f32x4 xv[8];
#pragma unroll
        for (int qi = 0; qi < 8; ++qi)
            xv[qi] = *(const f32x4*)&xt[(q0 + qi) * 256 + k4 * 4];
#pragma unroll
        for (int qi = 0; qi < 8; ++qi) {
            f32x4 a = acc[qi];
            const f32x4 x = xv[qi];
            a.x = fmaf(x.x, w[0].x, a.x); a.y = fmaf(x.x, w[0].y, a.y);
            a.z = fmaf(x.x, w[0].z, a.z); a.w = fmaf(x.x, w[0].w, a.w);
            a.x = fmaf(x.y, w[1].x, a.x); a.y = fmaf(x.y, w[1].y, a.y);
            a.z = fmaf(x.y, w[1].z, a.z); a.w = fmaf(x.y, w[1].w, a.w);
            a.x = fmaf(x.z, w[2].x, a.x); a.y = fmaf(x.z, w[2].y, a.y);
            a.z = fmaf(x.z, w[2].z, a.z); a.w = fmaf(x.z, w[2].w, a.w);
            a.x = fmaf(x.w, w[3].x, a.x); a.y = fmaf(x.w, w[3].y, a.y);
            a.z = fmaf(x.w, w[3].z, a.z); a.w = fmaf(x.w, w[3].w, a.w);
            acc[qi] = a;
        }
    }

    const f32x4 bv = *(const f32x4*)&bias[c0];
#pragma unroll
    for (int qi = 0; qi < 8; ++qi) {
        f32x4 o = acc[qi];
        o.x += bv.x; o.y += bv.y; o.z += bv.z; o.w += bv.w;
        *(f32x4*)&Y[(size_t)(row0 + q0 + qi) * M + c0] = o;
    }
}

// ---- spatial binning ----
#define NBINS 4096

__device__ __forceinline__ int bin_of(float ri, float rj) {
    int bi = (int)ri >> 3, bj = (int)rj >> 3;
    bi = min(63, max(0, bi)); bj = min(63, max(0, bj));
    return bi * 64 + bj;
}

__global__ void bin_hist(const float* __restrict__ refp, int* __restrict__ hist, int N) {
    const int n = blockIdx.x * blockDim.x + threadIdx.x;
    if (n < N) atomicAdd(&hist[bin_of(refp[2 * n], refp[2 * n + 1])], 1);
}

__global__ __launch_bounds__(256)
void bin_scan(const int* __restrict__ hist, int* __restrict__ binptr) {
    __shared__ int part[256];
    const int t = threadIdx.x;
    int vals[16], excl[16], run = 0;
#pragma unroll
    for (int i = 0; i < 16; ++i) { vals[i] = hist[t * 16 + i]; }
#pragma unroll
    for (int i = 0; i < 16; ++i) { excl[i] = run; run += vals[i]; }
    part[t] = run;
    __syncthreads();
    int off = 0;
    for (int i = 0; i < t; ++i) off += part[i];
#pragma unroll
    for (int i = 0; i < 16; ++i) binptr[t * 16 + i] = off + excl[i];
}

__global__ void bin_scatter(const float* __restrict__ refp, int* __restrict__ binptr,
                            int* __restrict__ perm, int N) {
    const int n = blockIdx.x * blockDim.x + threadIdx.x;
    if (n < N) {
        const int b = bin_of(refp[2 * n], refp[2 * n + 1]);
        const int pos = atomicAdd(&binptr[b], 1);
        perm[pos] = n;
    }
}

// ---- W_val swizzle into MFMA-fragment order ----
__global__ __launch_bounds__(256)
void prep_wvF(const float* __restrict__ W, f16* __restrict__ wvF) {
    const int k = blockIdx.x, n = threadIdx.x;
    const int ks = k >> 5, kg = (k >> 3) & 3, j = k & 7;
    const int tile = n >> 4, l15 = n & 15;
    const int lane = (kg << 4) | l15;
    wvF[((size_t)(ks * 16 + tile) * 512) + lane * 8 + j] = (f16)W[(size_t)k * 256 + n];
}

// ---- merged MFMA f16 projection over all 4 levels, 32-px tiles ------------
// Level boundaries (in 32-px blocks): l0:[0,256) l1:[256,1280) l2:[1280,5376)
// l3:[5376,21760).
__global__ __launch_bounds__(256)
void proj_val_all(const float* __restrict__ v0, const float* __restrict__ v1,
                  const float* __restrict__ v2, const float* __restrict__ v3,
                  const f16* __restrict__ wvF, const float* __restrict__ bval,
                  f16* __restrict__ vp0, f16* __restrict__ vp1,
                  f16* __restrict__ vp2, f16* __restrict__ vp3) {
    __shared__ f16 At[32][264];
    const int tid = threadIdx.x;

    const int bid = blockIdx.x;
    const float* V; f16* VP; long px0;
    if (bid < 256)        { V = v0; VP = vp0; px0 = (long)bid * 32; }
    else if (bid < 1280)  { V = v1; VP = vp1; px0 = (long)(bid - 256) * 32; }
    else if (bid < 5376)  { V = v2; VP = vp2; px0 = (long)(bid - 1280) * 32; }
    else                  { V = v3; VP = vp3; px0 = (long)(bid - 5376) * 32; }

    {
        const int wv_ = tid >> 6, ln_ = tid & 63;
#pragma unroll
        for (int i = 0; i < 8; ++i) {
            const int px = wv_ + i * 4;
            const float4 v4 = *(const float4*)(V + (px0 + px) * 256 + ln_ * 4);
            f16x4 h4 = {(f16)v4.x, (f16)v4.y, (f16)v4.z, (f16)v4.w};
            *(f16x4*)(&At[px][ln_ * 4]) = h4;
        }
    }
    __syncthreads();

    const int wave = tid >> 6, lane = tid & 63;
    const int l15 = lane & 15, kg = lane >> 4;

    f32x4 acc[2][4];   // [pxtile][chtile]
#pragma unroll
    for (int a = 0; a < 2; ++a)
#pragma unroll
        for (int b = 0; b < 4; ++b) acc[a][b] = (f32x4){0.f, 0.f, 0.f, 0.f};

#pragma unroll
    for (int ks = 0; ks < 8; ++ks) {
        f16x8 wf[4];
#pragma unroll
        for (int ct = 0; ct < 4; ++ct)
            wf[ct] = *(const f16x8*)(wvF + ((size_t)(ks * 16 + wave * 4 + ct) * 512) + lane * 8);
        f16x8 vf[2];
#pragma unroll
        for (int pt = 0; pt < 2; ++pt)
            vf[pt] = *(const f16x8*)(&At[pt * 16 + l15][ks * 32 + kg * 8]);
#pragma unroll
        for (int pt = 0; pt < 2; ++pt)
#pragma unroll
            for (int ct = 0; ct < 4; ++ct)
                acc[pt][ct] = __builtin_amdgcn_mfma_f32_16x16x32_f16(wf[ct], vf[pt], acc[pt][ct], 0, 0, 0);
    }

    __syncthreads();   // all waves done reading At -> reuse as out buffer

    const int ch0 = wave * 64;
#pragma unroll
    for (int ct = 0; ct < 4; ++ct) {
        const int chb = ch0 + ct * 16 + kg * 4;
        const float4 bv = *(const float4*)(bval + chb);
#pragma unroll
        for (int pt = 0; pt < 2; ++pt) {
            f16x4 o = {(f16)(acc[pt][ct].x + bv.x), (f16)(acc[pt][ct].y + bv.y),
                       (f16)(acc[pt][ct].z + bv.z), (f16)(acc[pt][ct].w + bv.w)};
            *(f16x4*)(&At[pt * 16 + l15][chb]) = o;
        }
    }
    __syncthreads();

    // coalesced copy-out: 32px x 512B contiguous in VP.
    f16* dst = VP + (size_t)px0 * 256;
#pragma unroll
    for (int i = 0; i < 4; ++i) {
        const int e0 = (i * 256 + tid) * 8;
        const int px = e0 >> 8;
        const int ch = e0 & 255;
        *(f16x8*)(dst + e0) = *(const f16x8*)(&At[px][ch]);
    }
}

// ---- gather from vp (byte-identical to r14/r15) ----------------------------
#define GQPB 8
__global__ __launch_bounds__(256)
void gather_vp(const float* __restrict__ offs_all,
               const float* __restrict__ logits_all,
               const float* __restrict__ refpts,
               const int* __restrict__ qoff, int n_off,
               const int* __restrict__ perm,
               const f16* __restrict__ vp0, const f16* __restrict__ vp1,
               const f16* __restrict__ vp2, const f16* __restrict__ vp3,
               float* __restrict__ val_out) {
    __shared__ float sOff[GQPB][256];
    __shared__ float sAttn[GQPB][128];
    __shared__ int   sQ[GQPB];
    const int tid = threadIdx.x;

    const int bid = blockIdx.x;
    const int cpx = gridDim.x >> 3;
    const int swz = (bid & 7) * cpx + (bid >> 3);
    const int n0p = swz * GQPB;

    if (tid < GQPB) sQ[tid] = perm[n0p + tid];
    __syncthreads();

    {
        const int q = tid >> 5, i = tid & 31;
        const int nq = sQ[q];
        ((f32x4*)sOff[q])[i]      = ((const f32x4*)(offs_all + (size_t)nq * 256))[i];
        ((f32x4*)sOff[q])[i + 32] = ((const f32x4*)(offs_all + (size_t)nq * 256))[i + 32];
        ((f32x4*)sAttn[q])[i]     = ((const f32x4*)(logits_all + (size_t)nq * 128))[i];
    }
    __syncthreads();

    if (tid < GQPB * 8) {
        float* row = &sAttn[tid >> 3][(tid & 7) * 16];
        float m = -1e30f;
#pragma unroll
        for (int i = 0; i < 16; ++i) m = fmaxf(m, row[i]);
        float s = 0.f;
#pragma unroll
        for (int i = 0; i < 16; ++i) { const float e = expf(row[i] - m); row[i] = e; s += e; }
        const float inv = 1.f / s;
#pragma unroll
        for (int i = 0; i < 16; ++i) row[i] *= inv;
    }
    __syncthreads();

    const int q = tid >> 5, h = (tid >> 2) & 7, s = tid & 3;
    const int n = sQ[q];
    int b = 0;
    for (int i = 1; i < n_off; ++i) if (n >= qoff[i]) b = i;
    const float ri = refpts[2 * n], rj = refpts[2 * n + 1];
    const int choff = h * 32 + s * 8;

    float acc[8];
#pragma unroll
    for (int j = 0; j < 8; ++j) acc[j] = 0.f;

#pragma unroll
    for (int l = 0; l < 4; ++l) {
        const int hw = (l == 0 ? 64 : (l == 1 ? 128 : (l == 2 ? 256 : 512)));
        const float sc = (float)hw * (1.0f / 512.0f);
        const f16* vbl = (l == 0 ? vp0 : (l == 1 ? vp1 : (l == 2 ? vp2 : vp3)));
        const f16* __restrict__ vb = vbl + (size_t)b * ((size_t)hw * hw * 256) + choff;

#pragma unroll
        for (int pp = 0; pp < 4; pp += 2) {
            int   o[8];
            float wgt[8];
#pragma unroll
            for (int pq = 0; pq < 2; ++pq) {
                const int p = pp + pq;
                const int oi = ((h * 4 + l) * 4 + p) * 2;
                const float fi = (ri + sOff[q][oi]) * sc;
                const float fj = (rj + sOff[q][oi + 1]) * sc;
                const float a = sAttn[q][(h * 4 + l) * 4 + p];
                const float sci = fmaxf(fi - 0.5f, 0.f);
                const float scj = fmaxf(fj - 0.5f, 0.f);
                const float fl_i = floorf(sci), fl_j = floorf(scj);
                const int i0 = (int)fl_i, j0 = (int)fl_j;
                const float fri = sci - fl_i, frj = scj - fl_j;
                const int i0c = min(i0, hw - 1), i1c = min(i0 + 1, hw - 1);
                const int j0c = min(j0, hw - 1), j1c = min(j0 + 1, hw - 1);
                const float uw = 1.f - fri, lw = 1.f - frj;
                o[pq * 4 + 0] = (i0c * hw + j0c) << 8;
                o[pq * 4 + 1] = (i0c * hw + j1c) << 8;
                o[pq * 4 + 2] = (i1c * hw + j0c) << 8;
                o[pq * 4 + 3] = (i1c * hw + j1c) << 8;
                wgt[pq * 4 + 0] = uw * lw * a;
                wgt[pq * 4 + 1] = uw * frj * a;
                wgt[pq * 4 + 2] = fri * lw * a;
                wgt[pq * 4 + 3] = fri * frj * a;
            }

            f16x8 buf[8];
#pragma unroll
            for (int k = 0; k < 8; ++k)
                buf[k] = *(const f16x8*)(vb + (size_t)o[k]);
            asm volatile("" : "+v"(buf[0]), "+v"(buf[1]), "+v"(buf[2]), "+v"(buf[3]),
                              "+v"(buf[4]), "+v"(buf[5]), "+v"(buf[6]), "+v"(buf[7])
                            :: "memory");
#pragma unroll
            for (int k = 0; k < 8; ++k) {
                const float wv = wgt[k];
#pragma unroll
                for (int j = 0; j < 8; ++j)
                    acc[j] = fmaf(wv, (float)buf[k][j], acc[j]);
            }
        }
    }

    float* op = val_out + (size_t)n * 256 + choff;
    *(f32x4*)op       = (f32x4){acc[0], acc[1], acc[2], acc[3]};
    *(f32x4*)(op + 4) = (f32x4){acc[4], acc[5], acc[6], acc[7]};
}

extern "C" void kernel_launch(void* const* d_in, const int* in_sizes, int n_in,
                              void* d_out, int out_size, void* d_ws, size_t ws_size,
                              hipStream_t stream) {
    const float* query  = (const float*)d_in[0];
    const int*   qoff   = (const int*)d_in[1];
    const float* refp   = (const float*)d_in[2];
    const float* v0     = (const float*)d_in[3];
    const float* v1     = (const float*)d_in[4];
    const float* v2     = (const float*)d_in[5];
    const float* v3     = (const float*)d_in[6];
    const float* W_off  = (const float*)d_in[7];
    const float* b_off  = (const float*)d_in[8];
    const float* W_attn = (const float*)d_in[9];
    const float* b_attn = (const float*)d_in[10];
    const float* W_val  = (const float*)d_in[11];
    const float* b_val  = (const float*)d_in[12];
    const float* W_out  = (const float*)d_in[13];
    const float* b_out  = (const float*)d_in[14];
    float* out = (float*)d_out;

    const int N = in_sizes[0] / 256;   // 16384
    const int n_off = in_sizes[1];     // 2

    float* P1off  = (float*)d_ws;                     // N*256 f32
    float* P1attn = P1off + (size_t)N * 256;          // N*128 f32
    int*   hist   = (int*)(P1attn + (size_t)N * 128); // NBINS
    int*   binptr = hist + NBINS;                     // NBINS
    int*   perm   = binptr + NBINS;                   // N

    const int M0 = 2 * 64 * 64, M1 = 2 * 128 * 128, M2 = 2 * 256 * 256, M3 = 2 * 512 * 512;
    const size_t base_b = (size_t)N * 256 * 4 + (size_t)N * 128 * 4 + (size_t)(2 * NBINS + N) * 4;

    hipMemsetAsync(hist, 0, NBINS * sizeof(int), stream);
    bin_hist<<<(N + 255) / 256, 256, 0, stream>>>(refp, hist, N);
    bin_scan<<<1, 256, 0, stream>>>(hist, binptr);
    bin_scatter<<<(N + 255) / 256, 256, 0, stream>>>(refp, binptr, perm, N);

    gemm_rb<256><<<N / 32, 256, 0, stream>>>(query, W_off, b_off, P1off);
    gemm_rb<128><<<N / 32, 128, 0, stream>>>(query, W_attn, b_attn, P1attn);

    f16* wvF = (f16*)((char*)d_ws + base_b);
    f16* vp0 = wvF + 65536;
    f16* vp1 = vp0 + (size_t)M0 * 256;
    f16* vp2 = vp1 + (size_t)M1 * 256;
    f16* vp3 = vp2 + (size_t)M2 * 256;

    prep_wvF<<<256, 256, 0, stream>>>(W_val, wvF);
    // merged projection: 256 + 1024 + 4096 + 16384 = 21760 blocks (32 px each)
    proj_val_all<<<21760, 256, 0, stream>>>(v0, v1, v2, v3, wvF, b_val,
                                            vp0, vp1, vp2, vp3);

    gather_vp<<<N / GQPB, 256, 0, stream>>>(P1off, P1attn, refp, qoff, n_off,
                                            perm, vp0, vp1, vp2, vp3, out);

    gemm_rb<256><<<N / 32, 256, 0, stream>>>(out, W_out, b_out, out);
}